// Round 14
// baseline (181.997 us; speedup 1.0000x reference)
//
#include <hip/hip_runtime.h>

// Trajectron sliding-window LSTM embed:
//   inputs [T=256, B=128, N=4, D=2] f32
//   his LSTM H=32 over n=3; int LSTM H=8 over n=0; window 64 ending at t
//   out[t,b,:] = [h_his | h_int] @ W_out.T + b_out   -> [256,128,2] f32
//
// Round-26 = Round-25 resubmitted verbatim (R13 was an infra failure; the
// kernel never ran; source re-audited: clamped prefetch row <= 255, in
// bounds). Branch-free body + unroll 2:
//   R24's unroll-2 was NULL with VGPR pinned at 80 -- the prefetch guard
//   `if (s+1 < nsteps)` split the body into basic blocks and the scheduler
//   won't migrate MFMAs across them. Fix: clamp the prefetch index
//   (sn = min(s+1, nsteps-1); scalar cselect, no CFG split). Last
//   iteration's prefetch is dead either way -> numerically identical.
//   With a straight-line 2-step region, iter-B's h-independent front
//   (x-prep, 8 AX MFMAs, int strand) can hoist into iter-A's his-tail
//   stall (~38% of the step-slot per R22/R23 counter arithmetic).
// Everything else byte-identical to verified R23/R24 (absmax 4.88e-4).

typedef float v4f __attribute__((ext_vector_type(4)));
typedef _Float16 h8v __attribute__((ext_vector_type(8)));

static __device__ __forceinline__ float fexp2(float x) {
    return __builtin_amdgcn_exp2f(x);
}
static __device__ __forceinline__ float frcp(float x) {
    return __builtin_amdgcn_rcpf(x);
}
static __device__ __forceinline__ unsigned short f2h(float f) {
    _Float16 h = (_Float16)f;
    unsigned short u;
    __builtin_memcpy(&u, &h, 2);
    return u;
}
static __device__ __forceinline__ float h2f(unsigned short u) {
    _Float16 h;
    __builtin_memcpy(&h, &u, 2);
    return (float)h;
}

#define LOG2E    1.442695041f
#define TWOLOG2E 2.885390082f
#define H16ONE   0x3C00u

// 7-trans LSTM unit update (5 exp2 + 2 rcp).
// Inputs are prescaled gate pre-activations: Di=-i*log2e, Df=-f*log2e,
// Dg=-2g*log2e, Do=-o*log2e (from the MFMA). c,h updated in place.
static __device__ __forceinline__ void lstm_unit(
    float Di, float Df, float Dg, float Do, float& c, float& h)
{
    const float ei = fminf(fexp2(Di), 1e12f);
    const float ef = fminf(fexp2(Df), 1e12f);
    const float eg = fminf(fexp2(Dg), 1e12f);
    const float eo = fminf(fexp2(Do), 1e18f);
    const float pi1 = 1.f + ei, pf1 = 1.f + ef, pg1 = 1.f + eg;
    const float p12 = pi1 * pg1;                  // (1+ei)(1+eg)
    const float r3  = frcp(p12 * pf1);            // <= 1e36, no INF
    const float cn  = fmaf(p12, c, (1.f - eg) * pf1) * r3;
    c = cn;
    const float ec = fminf(fexp2(TWOLOG2E * cn), 1e18f);
    h = (ec - 1.f) * frcp((1.f + eo) * (1.f + ec));
}

// ws layout:
//   ushort [0,4096)     hisAW : A-frags WhhP his, [T=8][n=16][k=32]
//   ushort [4096,8192)  hisAX : A-frags x-part his (k<8 used), [8][16][32]
//   ushort [8192,9216)  intAW : A-frags int (Whh+Wih+b in K-slots), [2][16][32]
//
// his perm: row p = T*16 + m (m = A-row = D-row): gate g = T>>1,
//   unit u = (m>>2)*8 + 4*(T&1) + (m&3), orig = g*32+u
// int perm: row p = T*16 + m: gate g = 2T + ((m&3)>>1),
//   unit u = 2*(m>>2) + (m&1), orig = g*8+u
// scale s = -log2e (i,f,o gates) / -2log2e (g gate)
__global__ __launch_bounds__(256) void prep_kernel(
    const float* __restrict__ Wih_his, const float* __restrict__ Whh_his,
    const float* __restrict__ bih_his, const float* __restrict__ bhh_his,
    const float* __restrict__ Wih_int, const float* __restrict__ Whh_int,
    const float* __restrict__ bih_int, const float* __restrict__ bhh_int,
    float* __restrict__ ws)
{
    const int i = blockIdx.x * 256 + threadIdx.x;
    unsigned short* wsu = reinterpret_cast<unsigned short*>(ws);

    if (i < 4096) {                     // hisAW: Whh part
        const int T = i >> 9, m = (i >> 5) & 15, k = i & 31;
        const int g = T >> 1;
        const int u = ((m >> 2) << 3) + ((T & 1) << 2) + (m & 3);
        const int orig = g * 32 + u;
        const float s = (g == 2) ? -TWOLOG2E : -LOG2E;
        wsu[i] = f2h(Whh_his[orig * 32 + k] * s);
    } else if (i < 8192) {              // hisAX: x-part (hi/lo exact)
        const int e = i - 4096;
        const int T = e >> 9, m = (e >> 5) & 15, k = e & 31;
        const int g = T >> 1;
        const int u = ((m >> 2) << 3) + ((T & 1) << 2) + (m & 3);
        const int orig = g * 32 + u;
        const float s = (g == 2) ? -TWOLOG2E : -LOG2E;
        const float w0 = Wih_his[orig * 2] * s;
        const float w1 = Wih_his[orig * 2 + 1] * s;
        const float b  = (bih_his[orig] + bhh_his[orig]) * s;
        unsigned short v = 0;
        switch (k) {
            case 0: v = f2h(w0); break;
            case 1: v = f2h(w1); break;
            case 2: v = f2h(b);  break;
            case 3: v = f2h(w0 - h2f(f2h(w0))); break;
            case 4: v = f2h(w1 - h2f(f2h(w1))); break;
            case 5: v = f2h(b  - h2f(f2h(b)));  break;
            case 6: v = f2h(w0); break;
            case 7: v = f2h(w1); break;
            default: v = 0; break;
        }
        wsu[4096 + e] = v;
    } else if (i < 9216) {              // intAW: Whh + Wih + b in K-slots
        const int e = i - 8192;
        const int T = e >> 9, m = (e >> 5) & 15, k = e & 31;
        const int q = k >> 3, j = k & 7;
        const int g = 2 * T + ((m & 3) >> 1);
        const int u = 2 * (m >> 2) + (m & 1);
        const int orig = g * 8 + u;
        const float s = (g == 2) ? -TWOLOG2E : -LOG2E;
        unsigned short v = 0;
        if (j < 6) {
            const int col = 2 * q + (j & 1);
            const float w = Whh_int[orig * 8 + col] * s;
            v = (j == 2 || j == 3) ? f2h(w - h2f(f2h(w))) : f2h(w);
        } else {
            const int comp = j & 1;
            if (q <= 1) {                       // w_hi . xh / w_hi . xl
                v = f2h(Wih_int[orig * 2 + comp] * s);
            } else if (q == 2) {                // w_lo . xh
                const float w = Wih_int[orig * 2 + comp] * s;
                v = f2h(w - h2f(f2h(w)));
            } else {                            // bias hi / lo
                const float b = (bih_int[orig] + bhh_int[orig]) * s;
                v = (comp == 0) ? f2h(b) : f2h(b - h2f(f2h(b)));
            }
        }
        wsu[8192 + e] = v;
    }
}

// ---------- fused his+int LSTM: 16 chains/wave, 18 MFMAs/step, no LDS ----
__global__ __launch_bounds__(64) void fusedw_kernel(
    const float* __restrict__ inp, const float* __restrict__ ws,
    const float* __restrict__ W_out, const float* __restrict__ b_out,
    float* __restrict__ out)
{
    const int lane = threadIdx.x;
    const int n    = lane & 15;
    const int q    = lane >> 4;
    const int Wd   = blockIdx.x;               // 0..2047
    const int t    = Wd >> 3;                  // uniform per wave
    const int bg   = Wd & 7;
    const int nsteps = (t >= 63) ? 64 : (t + 1);
    const int tau0   = (t >= 63) ? (t - 63) : 0;

    const unsigned short* wsu = reinterpret_cast<const unsigned short*>(ws);
    const h8v* wa = reinterpret_cast<const h8v*>(wsu);          // hisAW
    const h8v* wx = reinterpret_cast<const h8v*>(wsu + 4096);   // hisAX
    const h8v* wi = reinterpret_cast<const h8v*>(wsu + 8192);   // intAW
    h8v AW[8], AX[8], AI[2];
#pragma unroll
    for (int T = 0; T < 8; ++T) {
        AW[T] = wa[T * 64 + n * 4 + q];
        AX[T] = wx[T * 64 + n * 4 + q];
    }
#pragma unroll
    for (int T = 0; T < 2; ++T) AI[T] = wi[T * 64 + n * 4 + q];

    const int chain = bg * 16 + n;
    const float* xb0 = inp + chain * 8;        // base for indexed loads
    float2 xvH = *reinterpret_cast<const float2*>(xb0 + tau0 * 1024 + 6);
    float2 xvI = *reinterpret_cast<const float2*>(xb0 + tau0 * 1024);

    union BU { unsigned u[4]; h8v h; };
    BU bhH; bhH.u[0] = bhH.u[1] = bhH.u[2] = bhH.u[3] = 0;   // his h
    BU bhI; bhI.u[0] = bhI.u[1] = bhI.u[2] = bhI.u[3] = 0;   // int h
    float cH[8] = {0.f, 0.f, 0.f, 0.f, 0.f, 0.f, 0.f, 0.f};
    float hH[8] = {0.f, 0.f, 0.f, 0.f, 0.f, 0.f, 0.f, 0.f};
    float cI0 = 0.f, cI1 = 0.f, ih0 = 0.f, ih1 = 0.f;

#pragma unroll 2
    for (int s = 0; s < nsteps; ++s) {
        // branch-free prefetch: last iteration re-reads row t (dead value)
        const int sn = (s + 1 < nsteps) ? (s + 1) : (nsteps - 1);
        const float* xr = xb0 + (tau0 + sn) * 1024;
        const float2 xnH = *reinterpret_cast<const float2*>(xr + 6);
        const float2 xnI = *reinterpret_cast<const float2*>(xr);

        // his Bx: q0 lanes carry [xh, yh, 1, xh, yh, 1, xl, yl]; others 0
        BU bx;
        {
            const unsigned short xh = f2h(xvH.x), yh = f2h(xvH.y);
            const unsigned short xl = f2h(xvH.x - h2f(xh));
            const unsigned short yl = f2h(xvH.y - h2f(yh));
            bx.u[0] = ((unsigned)yh << 16) | xh;             // j1,j0
            bx.u[1] = ((unsigned)xh << 16) | H16ONE;         // j3=xh, j2=1
            bx.u[2] = (H16ONE << 16) | yh;                   // j5=1, j4=yh
            bx.u[3] = ((unsigned)yl << 16) | xl;             // j7,j6
            if (q != 0) { bx.u[0] = 0; bx.u[1] = 0; bx.u[2] = 0; bx.u[3] = 0; }
        }
        // int B x-slot: q0/q2 -> (xh,yh); q1 -> (xl,yl); q3 -> (1,1)
        {
            const unsigned short xh = f2h(xvI.x), yh = f2h(xvI.y);
            const unsigned short xl = f2h(xvI.x - h2f(xh));
            const unsigned short yl = f2h(xvI.y - h2f(yh));
            const unsigned ph = ((unsigned)yh << 16) | xh;
            const unsigned pl = ((unsigned)yl << 16) | xl;
            bhI.u[3] = (q == 3) ? ((H16ONE << 16) | H16ONE)
                                : ((q == 1) ? pl : ph);
        }

        const v4f z = {0.f, 0.f, 0.f, 0.f};

        // int: 2 MFMAs (fully independent of his chain)
        const v4f E0 = __builtin_amdgcn_mfma_f32_16x16x32_f16(AI[0], bhI.h, z, 0, 0, 0);
        const v4f E1 = __builtin_amdgcn_mfma_f32_16x16x32_f16(AI[1], bhI.h, z, 0, 0, 0);

        // his: 16 MFMAs D[T] = WhhP_T . h + WihP_T . [x;1]
        v4f D[8];
#pragma unroll
        for (int T = 0; T < 8; ++T) {
            const v4f cx = __builtin_amdgcn_mfma_f32_16x16x32_f16(AX[T], bx.h, z, 0, 0, 0);
            D[T] = __builtin_amdgcn_mfma_f32_16x16x32_f16(AW[T], bhH.h, cx, 0, 0, 0);
        }

        // int activations: units {2q, 2q+1} of chain n (7-trans form)
        lstm_unit(E0[0], E0[2], E1[0], E1[2], cI0, ih0);
        lstm_unit(E0[1], E0[3], E1[1], E1[3], cI1, ih1);

        // int h -> B-frag, in-lane (hi/lo corrected, rte-exact)
        {
            const unsigned short hh0 = f2h(ih0), hh1 = f2h(ih1);
            const unsigned short hl0 = f2h(ih0 - h2f(hh0));
            const unsigned short hl1 = f2h(ih1 - h2f(hh1));
            bhI.u[0] = ((unsigned)hh1 << 16) | hh0;
            bhI.u[1] = bhI.u[0];
            bhI.u[2] = ((unsigned)hl1 << 16) | hl0;
        }

        // his activations: 8 units (q*8+ww) of chain n (7-trans form)
#pragma unroll
        for (int hi = 0; hi < 2; ++hi) {
#pragma unroll
            for (int lo = 0; lo < 4; ++lo) {
                const int ww = hi * 4 + lo;
                lstm_unit(D[hi][lo], D[2 + hi][lo], D[4 + hi][lo],
                          D[6 + hi][lo], cH[ww], hH[ww]);
            }
        }
        // his h -> B-frag, in-lane (uncorrected: keep verified rte f2h)
#pragma unroll
        for (int d = 0; d < 4; ++d)
            bhH.u[d] = ((unsigned)f2h(hH[2 * d + 1]) << 16) | f2h(hH[2 * d]);

        xvH = xnH;
        xvI = xnI;
    }

    // ---- epilogue: combined projection, one q-reduction -----------------
    // his partial: units q*8..+7; int partial: units {2q,2q+1}
    const v4f w0a = *reinterpret_cast<const v4f*>(W_out + q * 8);
    const v4f w0b = *reinterpret_cast<const v4f*>(W_out + q * 8 + 4);
    const v4f w1a = *reinterpret_cast<const v4f*>(W_out + 40 + q * 8);
    const v4f w1b = *reinterpret_cast<const v4f*>(W_out + 40 + q * 8 + 4);
    float e0 = fmaf(W_out[33 + 2 * q], ih1, W_out[32 + 2 * q] * ih0);
    float e1 = fmaf(W_out[73 + 2 * q], ih1, W_out[72 + 2 * q] * ih0);
#pragma unroll
    for (int j = 0; j < 4; ++j) {
        e0 = fmaf(w0a[j], hH[j], fmaf(w0b[j], hH[4 + j], e0));
        e1 = fmaf(w1a[j], hH[j], fmaf(w1b[j], hH[4 + j], e1));
    }
    e0 += __shfl_xor(e0, 16); e1 += __shfl_xor(e1, 16);
    e0 += __shfl_xor(e0, 32); e1 += __shfl_xor(e1, 32);

    if (lane < 16) {
        float2 o;
        o.x = e0 + b_out[0];
        o.y = e1 + b_out[1];
        reinterpret_cast<float2*>(out)[t * 128 + chain] = o;
    }
}

extern "C" void kernel_launch(void* const* d_in, const int* in_sizes, int n_in,
                              void* d_out, int out_size, void* d_ws, size_t ws_size,
                              hipStream_t stream) {
    const float* inp     = (const float*)d_in[0];
    const float* Wih_his = (const float*)d_in[1];
    const float* Whh_his = (const float*)d_in[2];
    const float* bih_his = (const float*)d_in[3];
    const float* bhh_his = (const float*)d_in[4];
    const float* Wih_int = (const float*)d_in[5];
    const float* Whh_int = (const float*)d_in[6];
    const float* bih_int = (const float*)d_in[7];
    const float* bhh_int = (const float*)d_in[8];
    const float* W_out   = (const float*)d_in[9];
    const float* b_out   = (const float*)d_in[10];
    float* out  = (float*)d_out;
    float* ws   = (float*)d_ws;

    // pre-pass: build permuted fp16 A-frag tables (hi/lo exact splits)
    prep_kernel<<<dim3(36), dim3(256), 0, stream>>>(
        Wih_his, Whh_his, bih_his, bhh_his,
        Wih_int, Whh_int, bih_int, bhh_int, ws);

    // fused his+int LSTM: 2048 waves, 16 chains each, fence-free loop
    fusedw_kernel<<<dim3(2048), dim3(64), 0, stream>>>(
        inp, ws, W_out, b_out, out);
}

// Round 15
// 176.950 us; speedup vs baseline: 1.0285x; 1.0285x over previous
//
#include <hip/hip_runtime.h>

// Trajectron sliding-window LSTM embed:
//   inputs [T=256, B=128, N=4, D=2] f32
//   his LSTM H=32 over n=3; int LSTM H=8 over n=0; window 64 ending at t
//   out[t,b,:] = [h_his | h_int] @ W_out.T + b_out   -> [256,128,2] f32
//
// Round-27 (2-wave unit split): R24/R26 proved the compiler never overlaps
// across the step backedge (VGPR pinned, dur pinned ~122us, VALUBusy 62%).
// The 38% idle is per-wave dependency stall; at ~2 waves/SIMD the issue
// port idles whenever both waves stall together. Fix = more waves at the
// SAME total issue: split the his units across 2 waves per block
// (wave w owns units w*16..w*16+15 of all 16 chains; 4 units/lane ->
// 28 trans + 4 MFMA-pairs per wave-step, exactly half), exchanging h via
// a per-step LDS roundtrip: 1 ds_write_b64 + barrier + 1 ds_read_b128,
// stride 80 B (bank-conflict-free, 16-aligned). 2048 blocks x 2 waves =
// 4096 waves = 4/SIMD -> while one block waits at its barrier the other
// block issues (this is TLP hiding, NOT the R11/R16 single-wave fence
// that had nothing co-resident to hide it).
// his gate perm is now trivial: table row (w*4+Tl)*16+m <-> orig gate-row
// Tl*32 + w*16 + m (Tl = gate: 0=i,1=f,2=g,3=o; scale -2log2e for Tl=2).
// int LSTM lives wholly in wave 1 (R22 scheme, byte-identical). Epilogue:
// per-wave partial projection, q-shfl reduce, combine via 128 B LDS.
// Numerics: identical fp16 products and packing -> absmax ~4.88e-4.

typedef float v4f __attribute__((ext_vector_type(4)));
typedef _Float16 h8v __attribute__((ext_vector_type(8)));

static __device__ __forceinline__ float fexp2(float x) {
    return __builtin_amdgcn_exp2f(x);
}
static __device__ __forceinline__ float frcp(float x) {
    return __builtin_amdgcn_rcpf(x);
}
static __device__ __forceinline__ unsigned short f2h(float f) {
    _Float16 h = (_Float16)f;
    unsigned short u;
    __builtin_memcpy(&u, &h, 2);
    return u;
}
static __device__ __forceinline__ float h2f(unsigned short u) {
    _Float16 h;
    __builtin_memcpy(&h, &u, 2);
    return (float)h;
}

#define LOG2E    1.442695041f
#define TWOLOG2E 2.885390082f
#define H16ONE   0x3C00u

// 7-trans LSTM unit update (5 exp2 + 2 rcp).
// Inputs are prescaled gate pre-activations: Di=-i*log2e, Df=-f*log2e,
// Dg=-2g*log2e, Do=-o*log2e (from the MFMA). c,h updated in place.
static __device__ __forceinline__ void lstm_unit(
    float Di, float Df, float Dg, float Do, float& c, float& h)
{
    const float ei = fminf(fexp2(Di), 1e12f);
    const float ef = fminf(fexp2(Df), 1e12f);
    const float eg = fminf(fexp2(Dg), 1e12f);
    const float eo = fminf(fexp2(Do), 1e18f);
    const float pi1 = 1.f + ei, pf1 = 1.f + ef, pg1 = 1.f + eg;
    const float p12 = pi1 * pg1;                  // (1+ei)(1+eg)
    const float r3  = frcp(p12 * pf1);            // <= 1e36, no INF
    const float cn  = fmaf(p12, c, (1.f - eg) * pf1) * r3;
    c = cn;
    const float ec = fminf(fexp2(TWOLOG2E * cn), 1e18f);
    h = (ec - 1.f) * frcp((1.f + eo) * (1.f + ec));
}

// ws layout:
//   ushort [0,4096)     hisAW : [w*4+Tl][m][k=32] fp16, orig row
//                       Tl*32 + w*16 + m, scale by gate Tl
//   ushort [4096,8192)  hisAX : same rows, x-part in k<8 slots
//   ushort [8192,9216)  intAW : A-frags int (Whh+Wih+b in K-slots), [2][16][32]
// int perm (unchanged): row p = T*16 + m: gate g = 2T + ((m&3)>>1),
//   unit u = 2*(m>>2) + (m&1), orig = g*8+u
// scale s = -log2e (i,f,o gates) / -2log2e (g gate)
__global__ __launch_bounds__(256) void prep_kernel(
    const float* __restrict__ Wih_his, const float* __restrict__ Whh_his,
    const float* __restrict__ bih_his, const float* __restrict__ bhh_his,
    const float* __restrict__ Wih_int, const float* __restrict__ Whh_int,
    const float* __restrict__ bih_int, const float* __restrict__ bhh_int,
    float* __restrict__ ws)
{
    const int i = blockIdx.x * 256 + threadIdx.x;
    unsigned short* wsu = reinterpret_cast<unsigned short*>(ws);

    if (i < 4096) {                     // hisAW: Whh part
        const int T8 = i >> 9, m = (i >> 5) & 15, k = i & 31;
        const int w = T8 >> 2, Tl = T8 & 3;
        const int orig = Tl * 32 + w * 16 + m;
        const float s = (Tl == 2) ? -TWOLOG2E : -LOG2E;
        wsu[i] = f2h(Whh_his[orig * 32 + k] * s);
    } else if (i < 8192) {              // hisAX: x-part (hi/lo exact)
        const int e = i - 4096;
        const int T8 = e >> 9, m = (e >> 5) & 15, k = e & 31;
        const int w = T8 >> 2, Tl = T8 & 3;
        const int orig = Tl * 32 + w * 16 + m;
        const float s = (Tl == 2) ? -TWOLOG2E : -LOG2E;
        const float w0 = Wih_his[orig * 2] * s;
        const float w1 = Wih_his[orig * 2 + 1] * s;
        const float b  = (bih_his[orig] + bhh_his[orig]) * s;
        unsigned short v = 0;
        switch (k) {
            case 0: v = f2h(w0); break;
            case 1: v = f2h(w1); break;
            case 2: v = f2h(b);  break;
            case 3: v = f2h(w0 - h2f(f2h(w0))); break;
            case 4: v = f2h(w1 - h2f(f2h(w1))); break;
            case 5: v = f2h(b  - h2f(f2h(b)));  break;
            case 6: v = f2h(w0); break;
            case 7: v = f2h(w1); break;
            default: v = 0; break;
        }
        wsu[4096 + e] = v;
    } else if (i < 9216) {              // intAW: Whh + Wih + b in K-slots
        const int e = i - 8192;
        const int T = e >> 9, m = (e >> 5) & 15, k = e & 31;
        const int q = k >> 3, j = k & 7;
        const int g = 2 * T + ((m & 3) >> 1);
        const int u = 2 * (m >> 2) + (m & 1);
        const int orig = g * 8 + u;
        const float s = (g == 2) ? -TWOLOG2E : -LOG2E;
        unsigned short v = 0;
        if (j < 6) {
            const int col = 2 * q + (j & 1);
            const float w = Whh_int[orig * 8 + col] * s;
            v = (j == 2 || j == 3) ? f2h(w - h2f(f2h(w))) : f2h(w);
        } else {
            const int comp = j & 1;
            if (q <= 1) {                       // w_hi . xh / w_hi . xl
                v = f2h(Wih_int[orig * 2 + comp] * s);
            } else if (q == 2) {                // w_lo . xh
                const float w = Wih_int[orig * 2 + comp] * s;
                v = f2h(w - h2f(f2h(w)));
            } else {                            // bias hi / lo
                const float b = (bih_int[orig] + bhh_int[orig]) * s;
                v = (comp == 0) ? f2h(b) : f2h(b - h2f(f2h(b)));
            }
        }
        wsu[8192 + e] = v;
    }
}

// ---------- fused his+int LSTM: 2 waves/block, 4 units/lane each ---------
// Wave w owns his units w*16..+15 (lane(q,n): units w*16+q*4..+3, chain n).
// Per step: 8 MFMAs (4 AX + 4 AW), 4 lstm_units, h-exchange via LDS.
// Wave 1 additionally runs the whole int LSTM (R22 scheme).
__global__ __launch_bounds__(128, 4) void fused2_kernel(
    const float* __restrict__ inp, const float* __restrict__ ws,
    const float* __restrict__ W_out, const float* __restrict__ b_out,
    float* __restrict__ out)
{
    __shared__ __align__(16) unsigned char hb[2][1280];  // [dbuf][16 ch x 80 B]
    __shared__ float2 ebuf[16];

    const int tid  = threadIdx.x;
    const int w    = tid >> 6;                 // wave 0/1
    const int lane = tid & 63;
    const int n    = lane & 15;
    const int q    = lane >> 4;
    const int Wd   = blockIdx.x;               // 0..2047
    const int t    = Wd >> 3;                  // uniform per block
    const int bg   = Wd & 7;
    const int nsteps = (t >= 63) ? 64 : (t + 1);
    const int tau0   = (t >= 63) ? (t - 63) : 0;

    const unsigned short* wsu = reinterpret_cast<const unsigned short*>(ws);
    const h8v* wa = reinterpret_cast<const h8v*>(wsu);          // hisAW
    const h8v* wx = reinterpret_cast<const h8v*>(wsu + 4096);   // hisAX
    const h8v* wi = reinterpret_cast<const h8v*>(wsu + 8192);   // intAW
    h8v AW[4], AX[4], AI[2];
#pragma unroll
    for (int Tl = 0; Tl < 4; ++Tl) {
        AW[Tl] = wa[(w * 4 + Tl) * 64 + n * 4 + q];
        AX[Tl] = wx[(w * 4 + Tl) * 64 + n * 4 + q];
    }
#pragma unroll
    for (int T = 0; T < 2; ++T) AI[T] = wi[T * 64 + n * 4 + q];

    const int chain = bg * 16 + n;
    const float* xb0 = inp + chain * 8;
    float2 xvH = *reinterpret_cast<const float2*>(xb0 + tau0 * 1024 + 6);
    float2 xvI = *reinterpret_cast<const float2*>(xb0 + tau0 * 1024);

    union BU { unsigned u[4]; h8v h; };
    BU bh;  bh.u[0] = bh.u[1] = bh.u[2] = bh.u[3] = 0;     // his h B-frag
    BU bhI; bhI.u[0] = bhI.u[1] = bhI.u[2] = bhI.u[3] = 0; // int h (w1)
    float cH[4] = {0.f, 0.f, 0.f, 0.f};
    float hH[4] = {0.f, 0.f, 0.f, 0.f};
    float cI0 = 0.f, cI1 = 0.f, ih0 = 0.f, ih1 = 0.f;

    const int wb = n * 80 + w * 32 + q * 8;    // write: my 4 units
    const int rb = n * 80 + q * 16;            // read: my 8 B-slot units

#pragma unroll 1
    for (int s = 0; s < nsteps; ++s) {
        // branch-free prefetch (last iteration's value is dead)
        const int sn = (s + 1 < nsteps) ? (s + 1) : (nsteps - 1);
        const float* xr = xb0 + (tau0 + sn) * 1024;
        const float2 xnH = *reinterpret_cast<const float2*>(xr + 6);
        const float2 xnI = *reinterpret_cast<const float2*>(xr);

        // his Bx: q0 lanes carry [xh, yh, 1, xh, yh, 1, xl, yl]; others 0
        BU bx;
        {
            const unsigned short xh = f2h(xvH.x), yh = f2h(xvH.y);
            const unsigned short xl = f2h(xvH.x - h2f(xh));
            const unsigned short yl = f2h(xvH.y - h2f(yh));
            bx.u[0] = ((unsigned)yh << 16) | xh;             // j1,j0
            bx.u[1] = ((unsigned)xh << 16) | H16ONE;         // j3=xh, j2=1
            bx.u[2] = (H16ONE << 16) | yh;                   // j5=1, j4=yh
            bx.u[3] = ((unsigned)yl << 16) | xl;             // j7,j6
            if (q != 0) { bx.u[0] = 0; bx.u[1] = 0; bx.u[2] = 0; bx.u[3] = 0; }
        }

        const v4f z = {0.f, 0.f, 0.f, 0.f};

        // int LSTM (wave 1 only; wave-uniform branch)
        if (w == 1) {
            const unsigned short xh = f2h(xvI.x), yh = f2h(xvI.y);
            const unsigned short xl = f2h(xvI.x - h2f(xh));
            const unsigned short yl = f2h(xvI.y - h2f(yh));
            const unsigned ph = ((unsigned)yh << 16) | xh;
            const unsigned pl = ((unsigned)yl << 16) | xl;
            bhI.u[3] = (q == 3) ? ((H16ONE << 16) | H16ONE)
                                : ((q == 1) ? pl : ph);
            const v4f E0 = __builtin_amdgcn_mfma_f32_16x16x32_f16(AI[0], bhI.h, z, 0, 0, 0);
            const v4f E1 = __builtin_amdgcn_mfma_f32_16x16x32_f16(AI[1], bhI.h, z, 0, 0, 0);
            lstm_unit(E0[0], E0[2], E1[0], E1[2], cI0, ih0);
            lstm_unit(E0[1], E0[3], E1[1], E1[3], cI1, ih1);
            const unsigned short hh0 = f2h(ih0), hh1 = f2h(ih1);
            const unsigned short hl0 = f2h(ih0 - h2f(hh0));
            const unsigned short hl1 = f2h(ih1 - h2f(hh1));
            bhI.u[0] = ((unsigned)hh1 << 16) | hh0;
            bhI.u[1] = bhI.u[0];
            bhI.u[2] = ((unsigned)hl1 << 16) | hl0;
        }

        // his: 8 MFMAs D[Tl] = WhhP . h + WihP . [x;1]  (my 4 gate-tiles)
        v4f D[4];
#pragma unroll
        for (int Tl = 0; Tl < 4; ++Tl) {
            const v4f cx = __builtin_amdgcn_mfma_f32_16x16x32_f16(AX[Tl], bx.h, z, 0, 0, 0);
            D[Tl] = __builtin_amdgcn_mfma_f32_16x16x32_f16(AW[Tl], bh.h, cx, 0, 0, 0);
        }

        // activations: 4 units (w*16+q*4+r) of chain n; D[Tl][r] = gate Tl
#pragma unroll
        for (int r = 0; r < 4; ++r)
            lstm_unit(D[0][r], D[1][r], D[2][r], D[3][r], cH[r], hH[r]);

        // h exchange: write my 4 units (8 B), barrier, read my 8 B-slots
        {
            const unsigned p0 = ((unsigned)f2h(hH[1]) << 16) | f2h(hH[0]);
            const unsigned p1 = ((unsigned)f2h(hH[3]) << 16) | f2h(hH[2]);
            *reinterpret_cast<uint2*>(&hb[s & 1][wb]) = make_uint2(p0, p1);
        }
        __syncthreads();
        {
            const uint4 rv = *reinterpret_cast<const uint4*>(&hb[s & 1][rb]);
            bh.u[0] = rv.x; bh.u[1] = rv.y; bh.u[2] = rv.z; bh.u[3] = rv.w;
        }

        xvH = xnH;
        xvI = xnI;
    }

    // ---- epilogue: per-wave partial projection, combine via LDS ---------
    const int u0 = w * 16 + q * 4;
    float e0 = 0.f, e1 = 0.f;
#pragma unroll
    for (int r = 0; r < 4; ++r) {
        e0 = fmaf(W_out[u0 + r],      hH[r], e0);
        e1 = fmaf(W_out[40 + u0 + r], hH[r], e1);
    }
    if (w == 1) {
        e0 = fmaf(W_out[33 + 2 * q], ih1, fmaf(W_out[32 + 2 * q], ih0, e0));
        e1 = fmaf(W_out[73 + 2 * q], ih1, fmaf(W_out[72 + 2 * q], ih0, e1));
    }
    e0 += __shfl_xor(e0, 16); e1 += __shfl_xor(e1, 16);
    e0 += __shfl_xor(e0, 32); e1 += __shfl_xor(e1, 32);

    if (w == 1 && lane < 16) {
        float2 p; p.x = e0; p.y = e1;
        ebuf[n] = p;
    }
    __syncthreads();
    if (w == 0 && lane < 16) {
        const float2 p = ebuf[n];
        float2 o;
        o.x = e0 + p.x + b_out[0];
        o.y = e1 + p.y + b_out[1];
        reinterpret_cast<float2*>(out)[t * 128 + chain] = o;
    }
}

extern "C" void kernel_launch(void* const* d_in, const int* in_sizes, int n_in,
                              void* d_out, int out_size, void* d_ws, size_t ws_size,
                              hipStream_t stream) {
    const float* inp     = (const float*)d_in[0];
    const float* Wih_his = (const float*)d_in[1];
    const float* Whh_his = (const float*)d_in[2];
    const float* bih_his = (const float*)d_in[3];
    const float* bhh_his = (const float*)d_in[4];
    const float* Wih_int = (const float*)d_in[5];
    const float* Whh_int = (const float*)d_in[6];
    const float* bih_int = (const float*)d_in[7];
    const float* bhh_int = (const float*)d_in[8];
    const float* W_out   = (const float*)d_in[9];
    const float* b_out   = (const float*)d_in[10];
    float* out  = (float*)d_out;
    float* ws   = (float*)d_ws;

    // pre-pass: build permuted fp16 A-frag tables (hi/lo exact splits)
    prep_kernel<<<dim3(36), dim3(256), 0, stream>>>(
        Wih_his, Whh_his, bih_his, bhh_his,
        Wih_int, Whh_int, bih_int, bhh_int, ws);

    // fused his+int LSTM: 2048 blocks x 2 waves (unit-split), 4 waves/SIMD
    fused2_kernel<<<dim3(2048), dim3(128), 0, stream>>>(
        inp, ws, W_out, b_out, out);
}